// Round 1
// baseline (367.379 us; speedup 1.0000x reference)
//
#include <hip/hip_runtime.h>

typedef _Float16 f16;
typedef f16 f16x8 __attribute__((ext_vector_type(8)));
typedef f16 f16x4 __attribute__((ext_vector_type(4)));
typedef float f32x4 __attribute__((ext_vector_type(4)));

#define NTOK 4096

// ---------------- f32 -> f16 convert ----------------
__global__ void k_f2h(const float* __restrict__ in, f16* __restrict__ out, int n) {
  int i = (blockIdx.x * blockDim.x + threadIdx.x) * 4;
  int stride = gridDim.x * blockDim.x * 4;
  for (; i < n; i += stride) {
    float4 f = *(const float4*)(in + i);
    f16x4 h;
    h[0] = (f16)f.x; h[1] = (f16)f.y; h[2] = (f16)f.z; h[3] = (f16)f.w;
    *(f16x4*)(out + i) = h;
  }
}

// ---------------- generic C = A[M,K] * W[NC,K]^T MFMA GEMM ----------------
// mode 0: QKV epilogue -> scatter to Qb/Kb [bh][n][dd], Vtb [bh][dd][n]  (f16)
// mode 1: out epilogue -> d_out f32 [rows][256] + bias
__global__ __launch_bounds__(256) void k_gemm(
    const f16* __restrict__ A, const f16* __restrict__ W,
    int K, int mode,
    f16* __restrict__ Qb, f16* __restrict__ Kb, f16* __restrict__ Vtb,
    float* __restrict__ outF, const float* __restrict__ bias)
{
  __shared__ f16 Al[64 * 40];  // 64 rows x 32 k, row stride 40 (+16B pad)
  __shared__ f16 Wl[64 * 40];
  const int t = threadIdx.x;
  const int w = t >> 6, l = t & 63;
  const int lrow = l & 15, lk = l >> 4;
  const int m0 = blockIdx.y * 64, nc0 = blockIdx.x * 64;
  f32x4 acc[4] = {};
  const int srow = t >> 2, sseg = t & 3;
  for (int k0 = 0; k0 < K; k0 += 32) {
    __syncthreads();
    f16x8 av = *(const f16x8*)(A + (size_t)(m0 + srow) * K + k0 + sseg * 8);
    f16x8 wv = *(const f16x8*)(W + (size_t)(nc0 + srow) * K + k0 + sseg * 8);
    *(f16x8*)(Al + srow * 40 + sseg * 8) = av;
    *(f16x8*)(Wl + srow * 40 + sseg * 8) = wv;
    __syncthreads();
    f16x8 af = *(const f16x8*)(Al + (w * 16 + lrow) * 40 + lk * 8);
#pragma unroll
    for (int ct = 0; ct < 4; ++ct) {
      f16x8 bf = *(const f16x8*)(Wl + (ct * 16 + lrow) * 40 + lk * 8);
      acc[ct] = __builtin_amdgcn_mfma_f32_16x16x32_f16(af, bf, acc[ct], 0, 0, 0);
    }
  }
  const int nb = m0 + w * 16 + lk * 4;  // first of 4 consecutive output rows
  if (mode == 0) {
    const int b = nb >> 12, n = nb & 4095;
#pragma unroll
    for (int ct = 0; ct < 4; ++ct) {
      int gc = nc0 + ct * 16 + lrow;        // qkv channel in [0,768)
      int s = gc >> 8, h = (gc >> 6) & 3, dd = gc & 63;
      int bh = b * 4 + h;
      if (s == 2) {
        f16x4 v;
#pragma unroll
        for (int j = 0; j < 4; ++j) v[j] = (f16)acc[ct][j];
        *(f16x4*)(Vtb + ((size_t)bh * 64 + dd) * 4096 + n) = v;
      } else {
        f16* dst = (s == 0) ? Qb : Kb;
#pragma unroll
        for (int j = 0; j < 4; ++j)
          dst[((size_t)bh * 4096 + n + j) * 64 + dd] = (f16)acc[ct][j];
      }
    }
  } else {
#pragma unroll
    for (int ct = 0; ct < 4; ++ct) {
      int gc = nc0 + ct * 16 + lrow;
      float bv = bias[gc];
#pragma unroll
      for (int j = 0; j < 4; ++j)
        outF[(size_t)(nb + j) * 256 + gc] = acc[ct][j] + bv;
    }
  }
}

// ---------------- per-channel L2 norms over tokens ----------------
__global__ __launch_bounds__(256) void k_norms(
    const f16* __restrict__ Qb, const f16* __restrict__ Kb,
    const float* __restrict__ temp,
    float* __restrict__ invq, float* __restrict__ invk)
{
  int bh = blockIdx.x;
  int t = threadIdx.x;
  int dd = t & 63, part = t >> 6;
  const f16* qp = Qb + (size_t)bh * NTOK * 64;
  const f16* kp = Kb + (size_t)bh * NTOK * 64;
  float sq = 0.f, sk = 0.f;
  for (int n = part; n < NTOK; n += 4) {
    float q = (float)qp[(size_t)n * 64 + dd];
    float k = (float)kp[(size_t)n * 64 + dd];
    sq += q * q;
    sk += k * k;
  }
  __shared__ float rq[256], rk[256];
  rq[t] = sq; rk[t] = sk;
  __syncthreads();
  if (part == 0) {
    sq = rq[dd] + rq[64 + dd] + rq[128 + dd] + rq[192 + dd];
    sk = rk[dd] + rk[64 + dd] + rk[128 + dd] + rk[192 + dd];
    invq[bh * 64 + dd] = temp[bh & 3] / fmaxf(sqrtf(sq), 1e-12f);
    invk[bh * 64 + dd] = 1.0f / fmaxf(sqrtf(sk), 1e-12f);
  }
}

// ---------------- in-place scale of Q,K by inv norms ----------------
__global__ void k_scale(f16* __restrict__ Qb, f16* __restrict__ Kb,
                        const float* __restrict__ invq, const float* __restrict__ invk) {
  int i = blockIdx.x * blockDim.x + threadIdx.x;
  const int tot = 8 * NTOK * 64;
  int stride = gridDim.x * blockDim.x;
  for (; i < tot; i += stride) {
    int dd = i & 63, bh = i >> 18;
    Qb[i] = (f16)((float)Qb[i] * invq[bh * 64 + dd]);
    Kb[i] = (f16)((float)Kb[i] * invk[bh * 64 + dd]);
  }
}

// ---------------- flash attention (no-max online softmax, logits tiny) ----------------
__global__ __launch_bounds__(256) void k_flash(
    const f16* __restrict__ Qb, const f16* __restrict__ Kb,
    const f16* __restrict__ Vtb, f16* __restrict__ Y)
{
  __shared__ f16 Kl[64 * 72];       // [m][d], row stride 72 (+16B pad)
  __shared__ f16 Vl[64 * 72];       // [dd][m]
  __shared__ f16 Pl[4 * 16 * 72];   // per-wave [n][m]
  const int t = threadIdx.x, w = t >> 6, l = t & 63;
  const int lrow = l & 15, lk = l >> 4;
  // XCD-bijective swizzle: 512 blocks, 8 XCDs -> each XCD owns one (b,h)
  int nb2 = (blockIdx.x & 7) * 64 + (blockIdx.x >> 3);
  const int bh = nb2 >> 6, qb = nb2 & 63;
  const int n0 = qb * 64;
  const size_t base = (size_t)bh * NTOK * 64;
  f16x8 qf0, qf1;
  {
    size_t roff = base + (size_t)(n0 + w * 16 + lrow) * 64;
    qf0 = *(const f16x8*)(Qb + roff + lk * 8);
    qf1 = *(const f16x8*)(Qb + roff + 32 + lk * 8);
  }
  f32x4 oacc[4] = {};
  float ls0 = 0.f, ls1 = 0.f, ls2 = 0.f, ls3 = 0.f;
  f16* Pw = Pl + w * 16 * 72;
  const int srow = t >> 3, sseg = t & 7;
  for (int m0 = 0; m0 < NTOK; m0 += 64) {
    __syncthreads();
    {
      f16x8 k0v = *(const f16x8*)(Kb + base + (size_t)(m0 + srow) * 64 + sseg * 8);
      f16x8 k1v = *(const f16x8*)(Kb + base + (size_t)(m0 + srow + 32) * 64 + sseg * 8);
      f16x8 v0v = *(const f16x8*)(Vtb + base + (size_t)srow * 4096 + m0 + sseg * 8);
      f16x8 v1v = *(const f16x8*)(Vtb + base + (size_t)(srow + 32) * 4096 + m0 + sseg * 8);
      *(f16x8*)(Kl + srow * 72 + sseg * 8) = k0v;
      *(f16x8*)(Kl + (srow + 32) * 72 + sseg * 8) = k1v;
      *(f16x8*)(Vl + srow * 72 + sseg * 8) = v0v;
      *(f16x8*)(Vl + (srow + 32) * 72 + sseg * 8) = v1v;
    }
    __syncthreads();
    // S = Q K^T  (4 col tiles of 16, K-dim = 64 in two chunks)
    f32x4 sacc[4] = {};
#pragma unroll
    for (int mt = 0; mt < 4; ++mt) {
      f16x8 kf0 = *(const f16x8*)(Kl + (mt * 16 + lrow) * 72 + lk * 8);
      f16x8 kf1 = *(const f16x8*)(Kl + (mt * 16 + lrow) * 72 + 32 + lk * 8);
      sacc[mt] = __builtin_amdgcn_mfma_f32_16x16x32_f16(qf0, kf0, sacc[mt], 0, 0, 0);
      sacc[mt] = __builtin_amdgcn_mfma_f32_16x16x32_f16(qf1, kf1, sacc[mt], 0, 0, 0);
    }
    // P = exp(S); accumulate row-sum partials; stash P (transposed via LDS)
#pragma unroll
    for (int mt = 0; mt < 4; ++mt) {
      float p0 = __expf(sacc[mt][0]);
      float p1 = __expf(sacc[mt][1]);
      float p2 = __expf(sacc[mt][2]);
      float p3 = __expf(sacc[mt][3]);
      ls0 += p0; ls1 += p1; ls2 += p2; ls3 += p3;
      Pw[(lk * 4 + 0) * 72 + mt * 16 + lrow] = (f16)p0;
      Pw[(lk * 4 + 1) * 72 + mt * 16 + lrow] = (f16)p1;
      Pw[(lk * 4 + 2) * 72 + mt * 16 + lrow] = (f16)p2;
      Pw[(lk * 4 + 3) * 72 + mt * 16 + lrow] = (f16)p3;
    }
    // O += P * V^T   (A-frag = P re-read in MFMA-A layout; wave-private, no barrier)
    f16x8 pf0 = *(const f16x8*)(Pw + lrow * 72 + lk * 8);
    f16x8 pf1 = *(const f16x8*)(Pw + lrow * 72 + 32 + lk * 8);
#pragma unroll
    for (int dt = 0; dt < 4; ++dt) {
      f16x8 vf0 = *(const f16x8*)(Vl + (dt * 16 + lrow) * 72 + lk * 8);
      f16x8 vf1 = *(const f16x8*)(Vl + (dt * 16 + lrow) * 72 + 32 + lk * 8);
      oacc[dt] = __builtin_amdgcn_mfma_f32_16x16x32_f16(pf0, vf0, oacc[dt], 0, 0, 0);
      oacc[dt] = __builtin_amdgcn_mfma_f32_16x16x32_f16(pf1, vf1, oacc[dt], 0, 0, 0);
    }
  }
  // reduce row-sums across the 16 lanes sharing a row group
#pragma unroll
  for (int m = 1; m < 16; m <<= 1) {
    ls0 += __shfl_xor(ls0, m, 64);
    ls1 += __shfl_xor(ls1, m, 64);
    ls2 += __shfl_xor(ls2, m, 64);
    ls3 += __shfl_xor(ls3, m, 64);
  }
  float inv0 = 1.f / ls0, inv1 = 1.f / ls1, inv2 = 1.f / ls2, inv3 = 1.f / ls3;
  // epilogue: scrambled layout  Y[b][n'][c'],  n' = dd*64 + h*16 + (n>>8), c' = n&255
  const int b = bh >> 2, h = bh & 3;
  const int nbase = n0 + w * 16 + lk * 4;
  const int np_lo = h * 16 + (nbase >> 8);
  const int cp = nbase & 255;
#pragma unroll
  for (int dt = 0; dt < 4; ++dt) {
    int dd = dt * 16 + lrow;
    int np = dd * 64 + np_lo;
    f16x4 yv;
    yv[0] = (f16)(oacc[dt][0] * inv0);
    yv[1] = (f16)(oacc[dt][1] * inv1);
    yv[2] = (f16)(oacc[dt][2] * inv2);
    yv[3] = (f16)(oacc[dt][3] * inv3);
    *(f16x4*)(Y + ((size_t)b * 4096 + np) * 256 + cp) = yv;
  }
}

extern "C" void kernel_launch(void* const* d_in, const int* in_sizes, int n_in,
                              void* d_out, int out_size, void* d_ws, size_t ws_size,
                              hipStream_t stream)
{
  const float* x     = (const float*)d_in[0];   // [2,4096,256]
  const float* w_qkv = (const float*)d_in[1];   // [768,256]
  const float* w_out = (const float*)d_in[2];   // [256,256]
  const float* b_out = (const float*)d_in[3];   // [256]
  const float* temp  = (const float*)d_in[4];   // [4,1,1]

  char* ws = (char*)d_ws;
  f16*   xb    = (f16*)(ws);                                  // 2M f16 = 4MB
  f16*   wqkvb = (f16*)(ws + 4 * 1024 * 1024);                // 196608 f16
  f16*   woutb = (f16*)(ws + 4 * 1024 * 1024 + 512 * 1024);   // 65536 f16
  f16*   Qb    = (f16*)(ws + 5  * 1024 * 1024);               // [8][4096][64]
  f16*   Kb    = (f16*)(ws + 9  * 1024 * 1024);
  f16*   Vtb   = (f16*)(ws + 13 * 1024 * 1024);               // [8][64][4096]
  float* invq  = (float*)(ws + 17 * 1024 * 1024);             // 512 f32
  float* invk  = (float*)(ws + 17 * 1024 * 1024 + 4096);
  f16*   Y     = (f16*)(ws + 18 * 1024 * 1024);               // [2][4096][256]
  float* outF  = (float*)d_out;

  k_f2h<<<2048, 256, 0, stream>>>(x, xb, 2 * 4096 * 256);
  k_f2h<<<192, 256, 0, stream>>>(w_qkv, wqkvb, 768 * 256);
  k_f2h<<<64, 256, 0, stream>>>(w_out, woutb, 256 * 256);
  k_gemm<<<dim3(12, 128), 256, 0, stream>>>(xb, wqkvb, 256, 0, Qb, Kb, Vtb, nullptr, nullptr);
  k_norms<<<8, 256, 0, stream>>>(Qb, Kb, temp, invq, invk);
  k_scale<<<2048, 256, 0, stream>>>(Qb, Kb, invq, invk);
  k_flash<<<512, 256, 0, stream>>>(Qb, Kb, Vtb, Y);
  k_gemm<<<dim3(4, 128), 256, 0, stream>>>(Y, woutb, 256, 1, nullptr, nullptr, nullptr, outF, b_out);
}

// Round 2
// 145.897 us; speedup vs baseline: 2.5181x; 2.5181x over previous
//
#include <hip/hip_runtime.h>

typedef _Float16 f16;
typedef f16 f16x8 __attribute__((ext_vector_type(8)));
typedef f16 f16x4 __attribute__((ext_vector_type(4)));
typedef float f32x4 __attribute__((ext_vector_type(4)));

#define NTOK 4096

// ---------------- f32 -> f16 convert ----------------
__global__ void k_f2h(const float* __restrict__ in, f16* __restrict__ out, int n) {
  int i = (blockIdx.x * blockDim.x + threadIdx.x) * 4;
  int stride = gridDim.x * blockDim.x * 4;
  for (; i < n; i += stride) {
    float4 f = *(const float4*)(in + i);
    f16x4 h;
    h[0] = (f16)f.x; h[1] = (f16)f.y; h[2] = (f16)f.z; h[3] = (f16)f.w;
    *(f16x4*)(out + i) = h;
  }
}

// ---------------- generic C = A[M,K] * W[NC,K]^T MFMA GEMM ----------------
// mode 0: QKV epilogue -> scatter to Qb/Kb [bh][n][dd], Vtb [bh][dd][n]  (f16)
// mode 1: out epilogue -> d_out f32 [rows][256] + bias
__global__ __launch_bounds__(256) void k_gemm(
    const f16* __restrict__ A, const f16* __restrict__ W,
    int K, int mode,
    f16* __restrict__ Qb, f16* __restrict__ Kb, f16* __restrict__ Vtb,
    float* __restrict__ outF, const float* __restrict__ bias)
{
  __shared__ f16 Al[64 * 40];  // 64 rows x 32 k, row stride 40 (+16B pad)
  __shared__ f16 Wl[64 * 40];
  const int t = threadIdx.x;
  const int w = t >> 6, l = t & 63;
  const int lrow = l & 15, lk = l >> 4;
  const int m0 = blockIdx.y * 64, nc0 = blockIdx.x * 64;
  f32x4 acc[4] = {};
  const int srow = t >> 2, sseg = t & 3;
  for (int k0 = 0; k0 < K; k0 += 32) {
    __syncthreads();
    f16x8 av = *(const f16x8*)(A + (size_t)(m0 + srow) * K + k0 + sseg * 8);
    f16x8 wv = *(const f16x8*)(W + (size_t)(nc0 + srow) * K + k0 + sseg * 8);
    *(f16x8*)(Al + srow * 40 + sseg * 8) = av;
    *(f16x8*)(Wl + srow * 40 + sseg * 8) = wv;
    __syncthreads();
    f16x8 af = *(const f16x8*)(Al + (w * 16 + lrow) * 40 + lk * 8);
#pragma unroll
    for (int ct = 0; ct < 4; ++ct) {
      f16x8 bf = *(const f16x8*)(Wl + (ct * 16 + lrow) * 40 + lk * 8);
      acc[ct] = __builtin_amdgcn_mfma_f32_16x16x32_f16(af, bf, acc[ct], 0, 0, 0);
    }
  }
  const int nb = m0 + w * 16 + lk * 4;  // first of 4 consecutive output rows
  if (mode == 0) {
    const int b = nb >> 12, n = nb & 4095;
#pragma unroll
    for (int ct = 0; ct < 4; ++ct) {
      int gc = nc0 + ct * 16 + lrow;        // qkv channel in [0,768)
      int s = gc >> 8, h = (gc >> 6) & 3, dd = gc & 63;
      int bh = b * 4 + h;
      if (s == 2) {
        f16x4 v;
#pragma unroll
        for (int j = 0; j < 4; ++j) v[j] = (f16)acc[ct][j];
        *(f16x4*)(Vtb + ((size_t)bh * 64 + dd) * 4096 + n) = v;
      } else {
        f16* dst = (s == 0) ? Qb : Kb;
#pragma unroll
        for (int j = 0; j < 4; ++j)
          dst[((size_t)bh * 4096 + n + j) * 64 + dd] = (f16)acc[ct][j];
      }
    }
  } else {
#pragma unroll
    for (int ct = 0; ct < 4; ++ct) {
      int gc = nc0 + ct * 16 + lrow;
      float bv = bias[gc];
#pragma unroll
      for (int j = 0; j < 4; ++j)
        outF[(size_t)(nb + j) * 256 + gc] = acc[ct][j] + bv;
    }
  }
}

// ---------------- per-channel L2 norm partials over token slices ----------------
// grid: 256 blocks = 8 bh * 32 slices of 128 tokens
__global__ __launch_bounds__(256) void k_norm1(
    const f16* __restrict__ Qb, const f16* __restrict__ Kb,
    float* __restrict__ partQ, float* __restrict__ partK)
{
  const int bh = blockIdx.x >> 5, slice = blockIdx.x & 31;
  const int t = threadIdx.x;
  const int dd = t & 63, part = t >> 6;
  const f16* qp = Qb + (size_t)bh * NTOK * 64;
  const f16* kp = Kb + (size_t)bh * NTOK * 64;
  const int nlo = slice * 128;
  float sq = 0.f, sk = 0.f;
  for (int n = nlo + part; n < nlo + 128; n += 4) {
    float q = (float)qp[(size_t)n * 64 + dd];
    float k = (float)kp[(size_t)n * 64 + dd];
    sq += q * q;
    sk += k * k;
  }
  __shared__ float rq[256], rk[256];
  rq[t] = sq; rk[t] = sk;
  __syncthreads();
  if (part == 0) {
    sq = rq[dd] + rq[64 + dd] + rq[128 + dd] + rq[192 + dd];
    sk = rk[dd] + rk[64 + dd] + rk[128 + dd] + rk[192 + dd];
    partQ[(bh * 32 + slice) * 64 + dd] = sq;
    partK[(bh * 32 + slice) * 64 + dd] = sk;
  }
}

// ---------------- finalize inv norms ----------------
__global__ __launch_bounds__(512) void k_norm2(
    const float* __restrict__ partQ, const float* __restrict__ partK,
    const float* __restrict__ temp,
    float* __restrict__ invq, float* __restrict__ invk)
{
  const int t = threadIdx.x;            // 512 = 8 bh * 64 dd
  const int bh = t >> 6, dd = t & 63;
  float sq = 0.f, sk = 0.f;
#pragma unroll
  for (int s = 0; s < 32; ++s) {
    sq += partQ[(bh * 32 + s) * 64 + dd];
    sk += partK[(bh * 32 + s) * 64 + dd];
  }
  invq[t] = temp[bh & 3] / fmaxf(sqrtf(sq), 1e-12f);
  invk[t] = 1.0f / fmaxf(sqrtf(sk), 1e-12f);
}

// ---------------- in-place scale of Q,K by inv norms (f16x8 vectorized) ----------------
__global__ void k_scale(f16* __restrict__ Qb, f16* __restrict__ Kb,
                        const float* __restrict__ invq, const float* __restrict__ invk) {
  const int vi = blockIdx.x * blockDim.x + threadIdx.x;  // 262144 vectors of 8
  const int e = vi * 8;
  const int bh = e >> 18, dd0 = e & 63;
  const float* iq = invq + bh * 64 + dd0;
  const float* ik = invk + bh * 64 + dd0;
  f16x8 q = *(f16x8*)(Qb + e);
  f16x8 k = *(f16x8*)(Kb + e);
#pragma unroll
  for (int j = 0; j < 8; ++j) {
    q[j] = (f16)((float)q[j] * iq[j]);
    k[j] = (f16)((float)k[j] * ik[j]);
  }
  *(f16x8*)(Qb + e) = q;
  *(f16x8*)(Kb + e) = k;
}

// ---------------- flash attention (no-max online softmax, logits tiny) ----------------
__global__ __launch_bounds__(256) void k_flash(
    const f16* __restrict__ Qb, const f16* __restrict__ Kb,
    const f16* __restrict__ Vtb, f16* __restrict__ Y)
{
  __shared__ f16 Kl[64 * 72];       // [m][d], row stride 72 (+16B pad)
  __shared__ f16 Vl[64 * 72];       // [dd][m]
  __shared__ f16 Pl[4 * 16 * 72];   // per-wave [n][m]
  const int t = threadIdx.x, w = t >> 6, l = t & 63;
  const int lrow = l & 15, lk = l >> 4;
  // XCD-bijective swizzle: 512 blocks, 8 XCDs -> each XCD owns one (b,h)
  int nb2 = (blockIdx.x & 7) * 64 + (blockIdx.x >> 3);
  const int bh = nb2 >> 6, qb = nb2 & 63;
  const int n0 = qb * 64;
  const size_t base = (size_t)bh * NTOK * 64;
  f16x8 qf0, qf1;
  {
    size_t roff = base + (size_t)(n0 + w * 16 + lrow) * 64;
    qf0 = *(const f16x8*)(Qb + roff + lk * 8);
    qf1 = *(const f16x8*)(Qb + roff + 32 + lk * 8);
  }
  f32x4 oacc[4] = {};
  float ls0 = 0.f, ls1 = 0.f, ls2 = 0.f, ls3 = 0.f;
  f16* Pw = Pl + w * 16 * 72;
  const int srow = t >> 3, sseg = t & 7;
  for (int m0 = 0; m0 < NTOK; m0 += 64) {
    __syncthreads();
    {
      f16x8 k0v = *(const f16x8*)(Kb + base + (size_t)(m0 + srow) * 64 + sseg * 8);
      f16x8 k1v = *(const f16x8*)(Kb + base + (size_t)(m0 + srow + 32) * 64 + sseg * 8);
      f16x8 v0v = *(const f16x8*)(Vtb + base + (size_t)srow * 4096 + m0 + sseg * 8);
      f16x8 v1v = *(const f16x8*)(Vtb + base + (size_t)(srow + 32) * 4096 + m0 + sseg * 8);
      *(f16x8*)(Kl + srow * 72 + sseg * 8) = k0v;
      *(f16x8*)(Kl + (srow + 32) * 72 + sseg * 8) = k1v;
      *(f16x8*)(Vl + srow * 72 + sseg * 8) = v0v;
      *(f16x8*)(Vl + (srow + 32) * 72 + sseg * 8) = v1v;
    }
    __syncthreads();
    // S = Q K^T  (4 col tiles of 16, K-dim = 64 in two chunks)
    f32x4 sacc[4] = {};
#pragma unroll
    for (int mt = 0; mt < 4; ++mt) {
      f16x8 kf0 = *(const f16x8*)(Kl + (mt * 16 + lrow) * 72 + lk * 8);
      f16x8 kf1 = *(const f16x8*)(Kl + (mt * 16 + lrow) * 72 + 32 + lk * 8);
      sacc[mt] = __builtin_amdgcn_mfma_f32_16x16x32_f16(qf0, kf0, sacc[mt], 0, 0, 0);
      sacc[mt] = __builtin_amdgcn_mfma_f32_16x16x32_f16(qf1, kf1, sacc[mt], 0, 0, 0);
    }
    // P = exp(S); accumulate row-sum partials; stash P (transposed via LDS)
#pragma unroll
    for (int mt = 0; mt < 4; ++mt) {
      float p0 = __expf(sacc[mt][0]);
      float p1 = __expf(sacc[mt][1]);
      float p2 = __expf(sacc[mt][2]);
      float p3 = __expf(sacc[mt][3]);
      ls0 += p0; ls1 += p1; ls2 += p2; ls3 += p3;
      Pw[(lk * 4 + 0) * 72 + mt * 16 + lrow] = (f16)p0;
      Pw[(lk * 4 + 1) * 72 + mt * 16 + lrow] = (f16)p1;
      Pw[(lk * 4 + 2) * 72 + mt * 16 + lrow] = (f16)p2;
      Pw[(lk * 4 + 3) * 72 + mt * 16 + lrow] = (f16)p3;
    }
    // O += P * V^T   (A-frag = P re-read in MFMA-A layout; wave-private, no barrier)
    f16x8 pf0 = *(const f16x8*)(Pw + lrow * 72 + lk * 8);
    f16x8 pf1 = *(const f16x8*)(Pw + lrow * 72 + 32 + lk * 8);
#pragma unroll
    for (int dt = 0; dt < 4; ++dt) {
      f16x8 vf0 = *(const f16x8*)(Vl + (dt * 16 + lrow) * 72 + lk * 8);
      f16x8 vf1 = *(const f16x8*)(Vl + (dt * 16 + lrow) * 72 + 32 + lk * 8);
      oacc[dt] = __builtin_amdgcn_mfma_f32_16x16x32_f16(pf0, vf0, oacc[dt], 0, 0, 0);
      oacc[dt] = __builtin_amdgcn_mfma_f32_16x16x32_f16(pf1, vf1, oacc[dt], 0, 0, 0);
    }
  }
  // reduce row-sums across the 16 lanes sharing a row group
#pragma unroll
  for (int m = 1; m < 16; m <<= 1) {
    ls0 += __shfl_xor(ls0, m, 64);
    ls1 += __shfl_xor(ls1, m, 64);
    ls2 += __shfl_xor(ls2, m, 64);
    ls3 += __shfl_xor(ls3, m, 64);
  }
  float inv0 = 1.f / ls0, inv1 = 1.f / ls1, inv2 = 1.f / ls2, inv3 = 1.f / ls3;
  // epilogue: scrambled layout  Y[b][n'][c'],  n' = dd*64 + h*16 + (n>>8), c' = n&255
  const int b = bh >> 2, h = bh & 3;
  const int nbase = n0 + w * 16 + lk * 4;
  const int np_lo = h * 16 + (nbase >> 8);
  const int cp = nbase & 255;
#pragma unroll
  for (int dt = 0; dt < 4; ++dt) {
    int dd = dt * 16 + lrow;
    int np = dd * 64 + np_lo;
    f16x4 yv;
    yv[0] = (f16)(oacc[dt][0] * inv0);
    yv[1] = (f16)(oacc[dt][1] * inv1);
    yv[2] = (f16)(oacc[dt][2] * inv2);
    yv[3] = (f16)(oacc[dt][3] * inv3);
    *(f16x4*)(Y + ((size_t)b * 4096 + np) * 256 + cp) = yv;
  }
}

extern "C" void kernel_launch(void* const* d_in, const int* in_sizes, int n_in,
                              void* d_out, int out_size, void* d_ws, size_t ws_size,
                              hipStream_t stream)
{
  const float* x     = (const float*)d_in[0];   // [2,4096,256]
  const float* w_qkv = (const float*)d_in[1];   // [768,256]
  const float* w_out = (const float*)d_in[2];   // [256,256]
  const float* b_out = (const float*)d_in[3];   // [256]
  const float* temp  = (const float*)d_in[4];   // [4,1,1]

  char* ws = (char*)d_ws;
  f16*   xb    = (f16*)(ws);                                  // 2M f16 = 4MB
  f16*   wqkvb = (f16*)(ws + 4 * 1024 * 1024);                // 196608 f16
  f16*   woutb = (f16*)(ws + 4 * 1024 * 1024 + 512 * 1024);   // 65536 f16
  f16*   Qb    = (f16*)(ws + 5  * 1024 * 1024);               // [8][4096][64]
  f16*   Kb    = (f16*)(ws + 9  * 1024 * 1024);
  f16*   Vtb   = (f16*)(ws + 13 * 1024 * 1024);               // [8][64][4096]
  float* invq  = (float*)(ws + 17 * 1024 * 1024);             // 512 f32
  float* invk  = (float*)(ws + 17 * 1024 * 1024 + 4096);
  float* partQ = (float*)(ws + 17 * 1024 * 1024 + 8192);      // 16384 f32 = 64KB
  float* partK = (float*)(ws + 17 * 1024 * 1024 + 8192 + 65536);
  f16*   Y     = (f16*)(ws + 18 * 1024 * 1024);               // [2][4096][256]
  float* outF  = (float*)d_out;

  k_f2h<<<2048, 256, 0, stream>>>(x, xb, 2 * 4096 * 256);
  k_f2h<<<192, 256, 0, stream>>>(w_qkv, wqkvb, 768 * 256);
  k_f2h<<<64, 256, 0, stream>>>(w_out, woutb, 256 * 256);
  k_gemm<<<dim3(12, 128), 256, 0, stream>>>(xb, wqkvb, 256, 0, Qb, Kb, Vtb, nullptr, nullptr);
  k_norm1<<<256, 256, 0, stream>>>(Qb, Kb, partQ, partK);
  k_norm2<<<1, 512, 0, stream>>>(partQ, partK, temp, invq, invk);
  k_scale<<<1024, 256, 0, stream>>>(Qb, Kb, invq, invk);
  k_flash<<<512, 256, 0, stream>>>(Qb, Kb, Vtb, Y);
  k_gemm<<<dim3(4, 128), 256, 0, stream>>>(Y, woutb, 256, 1, nullptr, nullptr, nullptr, outF, b_out);
}

// Round 4
// 134.269 us; speedup vs baseline: 2.7361x; 1.0866x over previous
//
#include <hip/hip_runtime.h>

typedef _Float16 f16;
typedef f16 f16x8 __attribute__((ext_vector_type(8)));
typedef f16 f16x4 __attribute__((ext_vector_type(4)));
typedef __fp16 fp16x2 __attribute__((ext_vector_type(2)));
typedef float f32x4 __attribute__((ext_vector_type(4)));
typedef float f32x16 __attribute__((ext_vector_type(16)));
typedef unsigned int u32;

#define NTOK 4096

// ---------------- f32 -> f16 convert ----------------
__global__ void k_f2h(const float* __restrict__ in, f16* __restrict__ out, int n) {
  int i = (blockIdx.x * blockDim.x + threadIdx.x) * 4;
  int stride = gridDim.x * blockDim.x * 4;
  for (; i < n; i += stride) {
    float4 f = *(const float4*)(in + i);
    f16x4 h;
    h[0] = (f16)f.x; h[1] = (f16)f.y; h[2] = (f16)f.z; h[3] = (f16)f.w;
    *(f16x4*)(out + i) = h;
  }
}

// ---------------- generic C = A[M,K] * W[NC,K]^T MFMA GEMM ----------------
// mode 0: QKV epilogue -> scatter to Qb/Kb [bh][n][dd], Vtb [bh][dd][n]  (f16)
// mode 1: out epilogue -> d_out f32 [rows][256] + bias
__global__ __launch_bounds__(256) void k_gemm(
    const f16* __restrict__ A, const f16* __restrict__ W,
    int K, int mode,
    f16* __restrict__ Qb, f16* __restrict__ Kb, f16* __restrict__ Vtb,
    float* __restrict__ outF, const float* __restrict__ bias)
{
  __shared__ f16 Al[64 * 40];  // 64 rows x 32 k, row stride 40 (+16B pad)
  __shared__ f16 Wl[64 * 40];
  const int t = threadIdx.x;
  const int w = t >> 6, l = t & 63;
  const int lrow = l & 15, lk = l >> 4;
  const int m0 = blockIdx.y * 64, nc0 = blockIdx.x * 64;
  f32x4 acc[4] = {};
  const int srow = t >> 2, sseg = t & 3;
  for (int k0 = 0; k0 < K; k0 += 32) {
    __syncthreads();
    f16x8 av = *(const f16x8*)(A + (size_t)(m0 + srow) * K + k0 + sseg * 8);
    f16x8 wv = *(const f16x8*)(W + (size_t)(nc0 + srow) * K + k0 + sseg * 8);
    *(f16x8*)(Al + srow * 40 + sseg * 8) = av;
    *(f16x8*)(Wl + srow * 40 + sseg * 8) = wv;
    __syncthreads();
    f16x8 af = *(const f16x8*)(Al + (w * 16 + lrow) * 40 + lk * 8);
#pragma unroll
    for (int ct = 0; ct < 4; ++ct) {
      f16x8 bf = *(const f16x8*)(Wl + (ct * 16 + lrow) * 40 + lk * 8);
      acc[ct] = __builtin_amdgcn_mfma_f32_16x16x32_f16(af, bf, acc[ct], 0, 0, 0);
    }
  }
  const int nb = m0 + w * 16 + lk * 4;  // first of 4 consecutive output rows
  if (mode == 0) {
    const int b = nb >> 12, n = nb & 4095;
#pragma unroll
    for (int ct = 0; ct < 4; ++ct) {
      int gc = nc0 + ct * 16 + lrow;        // qkv channel in [0,768)
      int s = gc >> 8, h = (gc >> 6) & 3, dd = gc & 63;
      int bh = b * 4 + h;
      if (s == 2) {
        f16x4 v;
#pragma unroll
        for (int j = 0; j < 4; ++j) v[j] = (f16)acc[ct][j];
        *(f16x4*)(Vtb + ((size_t)bh * 64 + dd) * 4096 + n) = v;
      } else {
        f16* dst = (s == 0) ? Qb : Kb;
#pragma unroll
        for (int j = 0; j < 4; ++j)
          dst[((size_t)bh * 4096 + n + j) * 64 + dd] = (f16)acc[ct][j];
      }
    }
  } else {
#pragma unroll
    for (int ct = 0; ct < 4; ++ct) {
      int gc = nc0 + ct * 16 + lrow;
      float bv = bias[gc];
#pragma unroll
      for (int j = 0; j < 4; ++j)
        outF[(size_t)(nb + j) * 256 + gc] = acc[ct][j] + bv;
    }
  }
}

// ---------------- per-channel L2 norm partials over token slices ----------------
__global__ __launch_bounds__(256) void k_norm1(
    const f16* __restrict__ Qb, const f16* __restrict__ Kb,
    float* __restrict__ partQ, float* __restrict__ partK)
{
  const int bh = blockIdx.x >> 5, slice = blockIdx.x & 31;
  const int t = threadIdx.x;
  const int dd = t & 63, part = t >> 6;
  const f16* qp = Qb + (size_t)bh * NTOK * 64;
  const f16* kp = Kb + (size_t)bh * NTOK * 64;
  const int nlo = slice * 128;
  float sq = 0.f, sk = 0.f;
  for (int n = nlo + part; n < nlo + 128; n += 4) {
    float q = (float)qp[(size_t)n * 64 + dd];
    float k = (float)kp[(size_t)n * 64 + dd];
    sq += q * q;
    sk += k * k;
  }
  __shared__ float rq[256], rk[256];
  rq[t] = sq; rk[t] = sk;
  __syncthreads();
  if (part == 0) {
    sq = rq[dd] + rq[64 + dd] + rq[128 + dd] + rq[192 + dd];
    sk = rk[dd] + rk[64 + dd] + rk[128 + dd] + rk[192 + dd];
    partQ[(bh * 32 + slice) * 64 + dd] = sq;
    partK[(bh * 32 + slice) * 64 + dd] = sk;
  }
}

// ---------------- finalize inv norms (log2e*temp folded into invq) ----------------
__global__ __launch_bounds__(512) void k_norm2(
    const float* __restrict__ partQ, const float* __restrict__ partK,
    const float* __restrict__ temp,
    float* __restrict__ invq, float* __restrict__ invk)
{
  const int t = threadIdx.x;            // 512 = 8 bh * 64 dd
  const int bh = t >> 6, dd = t & 63;
  float sq = 0.f, sk = 0.f;
#pragma unroll
  for (int s = 0; s < 32; ++s) {
    sq += partQ[(bh * 32 + s) * 64 + dd];
    sk += partK[(bh * 32 + s) * 64 + dd];
  }
  invq[t] = temp[bh & 3] * 1.4426950408889634f / fmaxf(sqrtf(sq), 1e-12f);
  invk[t] = 1.0f / fmaxf(sqrtf(sk), 1e-12f);
}

// ---------------- in-place scale of Q,K by inv norms (f16x8 vectorized) ----------------
__global__ void k_scale(f16* __restrict__ Qb, f16* __restrict__ Kb,
                        const float* __restrict__ invq, const float* __restrict__ invk) {
  const int vi = blockIdx.x * blockDim.x + threadIdx.x;  // 262144 vectors of 8
  const int e = vi * 8;
  const int bh = e >> 18, dd0 = e & 63;
  const float* iq = invq + bh * 64 + dd0;
  const float* ik = invk + bh * 64 + dd0;
  f16x8 q = *(f16x8*)(Qb + e);
  f16x8 k = *(f16x8*)(Kb + e);
#pragma unroll
  for (int j = 0; j < 8; ++j) {
    q[j] = (f16)((float)q[j] * iq[j]);
    k[j] = (f16)((float)k[j] * ik[j]);
  }
  *(f16x8*)(Qb + e) = q;
  *(f16x8*)(Kb + e) = k;
}

// ---------------- flash attention, 32x32 MFMA, in-register softmax (T12) ----------------
// 4 waves: w = qs + 2*kh.  Wave owns 32 q-rows (qs half of QBLK=64) and 32-key
// half (kh) of each 64-key tile.  S^T = mfma(K,Q); P stays in registers via
// cvt_pkrtz + v_permlane32_swap_b32; O,ls combined additively across kh at end.
__device__ inline void plane_swap(u32& a, u32& b) {
  asm volatile("v_permlane32_swap_b32 %0, %1" : "+v"(a), "+v"(b));
}

__global__ __launch_bounds__(256) void k_flash32(
    const f16* __restrict__ Qb, const f16* __restrict__ Kb,
    const f16* __restrict__ Vtb, f16* __restrict__ Y)
{
  __shared__ f16 Kl[64 * 64];     // [m][dd], XOR-swizzled
  __shared__ f16 Vl[64 * 64];     // [dd][m], XOR-swizzled
  __shared__ float Osh[128 * 36]; // [qs*64+dd][n] partials, +pad stride 36
  __shared__ float Lsh[128];      // [kh*2+qs][n]
  const int t = threadIdx.x, w = t >> 6, l = t & 63;
  const int r = l & 31, hi = l >> 5;
  const int qs = w & 1, kh = w >> 1;
  // XCD-bijective swizzle: each XCD owns one (b,h)
  int nb2 = (blockIdx.x & 7) * 64 + (blockIdx.x >> 3);
  const int bh = nb2 >> 6, qt = nb2 & 63;
  const size_t base = (size_t)bh * NTOK * 64;
  const int nrow = qt * 64 + qs * 32 + r;
  // Q B-fragments (4 k-chunks of 16 over d=64), hoisted
  f16x8 qf0 = *(const f16x8*)(Qb + base + (size_t)nrow * 64 +  0 + hi * 8);
  f16x8 qf1 = *(const f16x8*)(Qb + base + (size_t)nrow * 64 + 16 + hi * 8);
  f16x8 qf2 = *(const f16x8*)(Qb + base + (size_t)nrow * 64 + 32 + hi * 8);
  f16x8 qf3 = *(const f16x8*)(Qb + base + (size_t)nrow * 64 + 48 + hi * 8);
  f32x16 oacc0 = {}, oacc1 = {};
  float lsw = 0.f;
  const int srow = t >> 3, sseg = t & 7;
  const int swz = 8 * (sseg ^ (srow & 7));   // staging XOR swizzle (elements)
  const int rx = (r & 7) * 8;                // read-side XOR (elements)
  for (int m0 = 0; m0 < NTOK; m0 += 64) {
    __syncthreads();
    {
      f16x8 k0 = *(const f16x8*)(Kb + base + (size_t)(m0 + srow) * 64 + sseg * 8);
      f16x8 k1 = *(const f16x8*)(Kb + base + (size_t)(m0 + srow + 32) * 64 + sseg * 8);
      f16x8 v0 = *(const f16x8*)(Vtb + base + (size_t)srow * 4096 + m0 + sseg * 8);
      f16x8 v1 = *(const f16x8*)(Vtb + base + (size_t)(srow + 32) * 4096 + m0 + sseg * 8);
      *(f16x8*)(Kl + srow * 64 + swz) = k0;
      *(f16x8*)(Kl + (srow + 32) * 64 + swz) = k1;
      *(f16x8*)(Vl + srow * 64 + swz) = v0;
      *(f16x8*)(Vl + (srow + 32) * 64 + swz) = v1;
    }
    __syncthreads();
    // S^T[m][n] = sum_dd K[m][dd] Q[n][dd]; wave's m-rows = kh*32 + r
    f32x16 sacc = {};
    {
      const int krow = (kh * 32 + r) * 64;
      f16x8 kf0 = *(const f16x8*)(Kl + krow + (( 0 + hi * 8) ^ rx));
      f16x8 kf1 = *(const f16x8*)(Kl + krow + ((16 + hi * 8) ^ rx));
      f16x8 kf2 = *(const f16x8*)(Kl + krow + ((32 + hi * 8) ^ rx));
      f16x8 kf3 = *(const f16x8*)(Kl + krow + ((48 + hi * 8) ^ rx));
      sacc = __builtin_amdgcn_mfma_f32_32x32x16_f16(kf0, qf0, sacc, 0, 0, 0);
      sacc = __builtin_amdgcn_mfma_f32_32x32x16_f16(kf1, qf1, sacc, 0, 0, 0);
      sacc = __builtin_amdgcn_mfma_f32_32x32x16_f16(kf2, qf2, sacc, 0, 0, 0);
      sacc = __builtin_amdgcn_mfma_f32_32x32x16_f16(kf3, qf3, sacc, 0, 0, 0);
    }
    // P = exp2(S^T) in-register; pack pairs; D[u][v] holds m-offsets {8u+2v+4hi, +1}
    u32 Dw[8];
#pragma unroll
    for (int u = 0; u < 4; ++u) {
#pragma unroll
      for (int v = 0; v < 2; ++v) {
        float a = exp2f(sacc[u * 4 + v * 2]);
        float b2 = exp2f(sacc[u * 4 + v * 2 + 1]);
        lsw += a + b2;
        union { fp16x2 h; u32 u; } cv;
        cv.h = __builtin_amdgcn_cvt_pkrtz(a, b2);
        Dw[u * 2 + v] = cv.u;
      }
    }
    plane_swap(Dw[0], Dw[2]);  // chunk0: D[0][0] <-> D[1][0]
    plane_swap(Dw[1], Dw[3]);
    plane_swap(Dw[4], Dw[6]);  // chunk1: D[2][v] <-> D[3][v]
    plane_swap(Dw[5], Dw[7]);
    union { f16x8 v; u32 d[4]; } p0, p1;
    p0.d[0] = Dw[0]; p0.d[1] = Dw[1]; p0.d[2] = Dw[2]; p0.d[3] = Dw[3];
    p1.d[0] = Dw[4]; p1.d[1] = Dw[5]; p1.d[2] = Dw[6]; p1.d[3] = Dw[7];
    // O[n][dd] += P[n][m] * V[dd][m]
    {
      const int cb = kh * 32;
      f16x8 vf00 = *(const f16x8*)(Vl + (r)      * 64 + ((cb +  0 + hi * 8) ^ rx));
      f16x8 vf01 = *(const f16x8*)(Vl + (r)      * 64 + ((cb + 16 + hi * 8) ^ rx));
      f16x8 vf10 = *(const f16x8*)(Vl + (32 + r) * 64 + ((cb +  0 + hi * 8) ^ rx));
      f16x8 vf11 = *(const f16x8*)(Vl + (32 + r) * 64 + ((cb + 16 + hi * 8) ^ rx));
      oacc0 = __builtin_amdgcn_mfma_f32_32x32x16_f16(p0.v, vf00, oacc0, 0, 0, 0);
      oacc0 = __builtin_amdgcn_mfma_f32_32x32x16_f16(p1.v, vf01, oacc0, 0, 0, 0);
      oacc1 = __builtin_amdgcn_mfma_f32_32x32x16_f16(p0.v, vf10, oacc1, 0, 0, 0);
      oacc1 = __builtin_amdgcn_mfma_f32_32x32x16_f16(p1.v, vf11, oacc1, 0, 0, 0);
    }
  }
  // combine ls across hi halves (same query col n=r)
  lsw += __shfl_xor(lsw, 32, 64);
  if (kh == 0) {
    // write partial O (transposed [dd][n] for vector stores) and ls
#pragma unroll
    for (int dt = 0; dt < 2; ++dt) {
      float* orow = Osh + (qs * 64 + dt * 32 + r) * 36;
      const f32x16& oa = dt ? oacc1 : oacc0;
#pragma unroll
      for (int u = 0; u < 4; ++u) {
        f32x4 q4;
        q4[0] = oa[u * 4 + 0]; q4[1] = oa[u * 4 + 1];
        q4[2] = oa[u * 4 + 2]; q4[3] = oa[u * 4 + 3];
        *(f32x4*)(orow + u * 8 + hi * 4) = q4;
      }
    }
    if (hi == 0) Lsh[qs * 32 + r] = lsw;
  } else {
    if (hi == 0) Lsh[(2 + qs) * 32 + r] = lsw;
  }
  __syncthreads();
  if (kh == 1) {
    const int b = bh >> 2, h = bh & 3;
#pragma unroll
    for (int dt = 0; dt < 2; ++dt) {
      const int dd = dt * 32 + r;
      const float* orow = Osh + (qs * 64 + dd) * 36;
      const f32x16& oa = dt ? oacc1 : oacc0;
#pragma unroll
      for (int u = 0; u < 4; ++u) {
        f32x4 part = *(const f32x4*)(orow + u * 8 + hi * 4);
        f32x4 lA = *(const f32x4*)(Lsh + qs * 32 + u * 8 + hi * 4);
        f32x4 lB = *(const f32x4*)(Lsh + (2 + qs) * 32 + u * 8 + hi * 4);
        const int ng = qt * 64 + qs * 32 + u * 8 + hi * 4;  // first of 4 q-rows
        const int np = dd * 64 + h * 16 + (ng >> 8);
        const int cp = ng & 255;
        f16x4 yv;
#pragma unroll
        for (int j = 0; j < 4; ++j)
          yv[j] = (f16)((oa[u * 4 + j] + part[j]) / (lA[j] + lB[j]));
        *(f16x4*)(Y + ((size_t)b * 4096 + np) * 256 + cp) = yv;
      }
    }
  }
}

extern "C" void kernel_launch(void* const* d_in, const int* in_sizes, int n_in,
                              void* d_out, int out_size, void* d_ws, size_t ws_size,
                              hipStream_t stream)
{
  const float* x     = (const float*)d_in[0];   // [2,4096,256]
  const float* w_qkv = (const float*)d_in[1];   // [768,256]
  const float* w_out = (const float*)d_in[2];   // [256,256]
  const float* b_out = (const float*)d_in[3];   // [256]
  const float* temp  = (const float*)d_in[4];   // [4,1,1]

  char* ws = (char*)d_ws;
  f16*   xb    = (f16*)(ws);                                  // 2M f16 = 4MB
  f16*   wqkvb = (f16*)(ws + 4 * 1024 * 1024);                // 196608 f16
  f16*   woutb = (f16*)(ws + 4 * 1024 * 1024 + 512 * 1024);   // 65536 f16
  f16*   Qb    = (f16*)(ws + 5  * 1024 * 1024);               // [8][4096][64]
  f16*   Kb    = (f16*)(ws + 9  * 1024 * 1024);
  f16*   Vtb   = (f16*)(ws + 13 * 1024 * 1024);               // [8][64][4096]
  float* invq  = (float*)(ws + 17 * 1024 * 1024);             // 512 f32
  float* invk  = (float*)(ws + 17 * 1024 * 1024 + 4096);
  float* partQ = (float*)(ws + 17 * 1024 * 1024 + 8192);      // 16384 f32 = 64KB
  float* partK = (float*)(ws + 17 * 1024 * 1024 + 8192 + 65536);
  f16*   Y     = (f16*)(ws + 18 * 1024 * 1024);               // [2][4096][256]
  float* outF  = (float*)d_out;

  k_f2h<<<2048, 256, 0, stream>>>(x, xb, 2 * 4096 * 256);
  k_f2h<<<192, 256, 0, stream>>>(w_qkv, wqkvb, 768 * 256);
  k_f2h<<<64, 256, 0, stream>>>(w_out, woutb, 256 * 256);
  k_gemm<<<dim3(12, 128), 256, 0, stream>>>(xb, wqkvb, 256, 0, Qb, Kb, Vtb, nullptr, nullptr);
  k_norm1<<<256, 256, 0, stream>>>(Qb, Kb, partQ, partK);
  k_norm2<<<1, 512, 0, stream>>>(partQ, partK, temp, invq, invk);
  k_scale<<<1024, 256, 0, stream>>>(Qb, Kb, invq, invk);
  k_flash32<<<512, 256, 0, stream>>>(Qb, Kb, Vtb, Y);
  k_gemm<<<dim3(4, 128), 256, 0, stream>>>(Y, woutb, 256, 1, nullptr, nullptr, nullptr, outF, b_out);
}